// Round 8
// baseline (5726.262 us; speedup 1.0000x reference)
//
#include <hip/hip_runtime.h>
#include <hip/hip_bf16.h>

// ---------------------------------------------------------------------------
// BasicDGCNN forward, MI355X (gfx950). Inputs f32, output f32.
// Output layout (f32, flat): [0,768) vertex | [768,772) num_vertices |
// [772,776) nvs | [776,1800) gfeat | [1800,..) x_concat [4,8192,224].
//
// Round-19: phase A does ZERO exact work and ZERO divergent LDS reads (the
// two measured killers of r13-r18). Scan = 2-j x 4-acc approx dot; keep
// a[21] approx VALUES in registers; survivors (da < a[20]+marg) go to a
// stride-1 LDS ring (M=28) pruned against the monotone threshold; final
// ring = j-ascending superset of the split's exact top-21, emitted in the
// r17 [cnt|list] format (ovf -> 0xFFFF -> phase B full rescan, sound).
// marg = 2^-14*(xxi+xxmax_split): 8x slack over the rigorous f32
// reassociation bound 2*gamma_64*(xxi+xxj) -- r18 measured ~0 false passes
// at this scale. Uniform per split => ring pruning monotone-sound. Phase B
// (r17's proven knn_merge) recomputes exactly (byte-identical r12 chains)
// and inserts with strict < => final idx bit-identical => absmax 0.2949219.
// D=5 keeps the r12 exact path (emits exact top-21, same format).
// ---------------------------------------------------------------------------

#define NPTS 8192
#define BATCH 4
#define KNBR 20

// ===================== KNN phase A: per-split superset =====================
// grid (ROWS/128, S); block 128 thr. thread = query point; j-range
// [s*JC,(s+1)*JC) staged in TJ-row LDS tiles (XOR-swizzled float4 chunks).
template <int D, int RS, int S, int TJ, int M>
__global__ __launch_bounds__(128, 2) void knn_part(
    const float* feat, float* xcat) {
    constexpr bool PRE = (D % 4 == 0);
    constexpr int B5 = 8;                      // r12 buffer (D=5 path)
    __shared__ float xj[TJ * D];
    __shared__ float xxj[TJ];
    __shared__ float ringd[PRE ? M * 128 : 1];
    __shared__ unsigned short ringj[PRE ? M * 128 : 1];
    __shared__ float rmax[128];
    __shared__ float bufd[PRE ? 1 : B5 * 128];
    __shared__ unsigned short bufj[PRE ? 1 : B5 * 128];
    const int JC = NPTS / S;

    int gi = blockIdx.x * 128 + threadIdx.x;
    int s  = blockIdx.y;
    int b  = gi >> 13;
    int ib = gi & (NPTS - 1);
    const float* fb = feat + (size_t)b * NPTS * RS;
    int tid = threadIdx.x;
    const int sbase = s * JC;

    float xi[D];
    if (PRE) {
        #pragma unroll
        for (int c4 = 0; c4 < D / 4; ++c4) {
            float4 v = *(const float4*)(fb + (size_t)ib * RS + 4 * c4);
            xi[4 * c4] = v.x; xi[4 * c4 + 1] = v.y;
            xi[4 * c4 + 2] = v.z; xi[4 * c4 + 3] = v.w;
        }
    } else {
        #pragma unroll
        for (int c = 0; c < D; ++c) xi[c] = fb[(size_t)ib * RS + c];
    }
    float xxi = 0.f;
    #pragma unroll
    for (int c = 0; c < D; ++c) xxi = fmaf(xi[c], xi[c], xxi);

    unsigned short* sc16 =
        (unsigned short*)(xcat + (size_t)gi * 224 + 96) + s * 32;

    if (PRE) {
        // ---- upfront split xxmax (margins only; L2/L3-hot re-read) ----
        float mx = 0.f;
        for (int r = tid; r < JC; r += 128) {
            const float* row = fb + (size_t)(sbase + r) * RS;
            float sm = 0.f;
            #pragma unroll
            for (int c4 = 0; c4 < D / 4; ++c4) {
                float4 v = *(const float4*)(row + 4 * c4);
                sm = fmaf(v.x, v.x, sm); sm = fmaf(v.y, v.y, sm);
                sm = fmaf(v.z, v.z, sm); sm = fmaf(v.w, v.w, sm);
            }
            mx = fmaxf(mx, sm);
        }
        rmax[tid] = mx;
        __syncthreads();
        #pragma unroll
        for (int off = 64; off >= 1; off >>= 1) {
            if (tid < off) rmax[tid] = fmaxf(rmax[tid], rmax[tid + off]);
            __syncthreads();
        }
        // 2^-14*(xxi+xxmax): 8x slack over 2*gamma_64 reassociation bound
        const float marg = 6.103515625e-05f * (xxi + rmax[0]);

        float a[21];
        #pragma unroll
        for (int t = 0; t < 21; ++t) a[t] = __builtin_inff();
        auto chain = [&](float v) {
            if (v < a[20]) {
                a[20] = v;
                #pragma unroll
                for (int t = 20; t > 0; --t)
                    if (a[t] < a[t - 1]) {
                        float tv = a[t]; a[t] = a[t - 1]; a[t - 1] = tv;
                    }
            }
        };

        int  cnt = 0;
        bool ovf = false;
        auto compactAll = [&]() {          // uniform M-iter loop, stride-1
            float thr_c = a[20] + marg;
            int nc = 0;
            #pragma unroll 1
            for (int u = 0; u < M; ++u) {
                if (u < cnt) {
                    float dv = ringd[u * 128 + tid];
                    if (dv < thr_c) {
                        if (nc != u) {
                            ringd[nc * 128 + tid] = dv;
                            ringj[nc * 128 + tid] = ringj[u * 128 + tid];
                        }
                        ++nc;
                    }
                }
            }
            cnt = nc;
        };

        #pragma unroll 1
        for (int t0 = sbase; t0 < sbase + JC; t0 += TJ) {
            __syncthreads();               // protect prior-tile xj reads
            for (int e = tid; e < TJ * (D / 4); e += 128) {
                int r = e / (D / 4), c4 = e % (D / 4);
                float4 v = *(const float4*)(fb + (size_t)(t0 + r) * RS + 4 * c4);
                *(float4*)(xj + (size_t)r * D + (((c4 ^ (r & 7))) * 4)) = v;
            }
            if (tid < TJ) {                // per-row norm (== phase B chain)
                const float* row = fb + (size_t)(t0 + tid) * RS;
                float sm = 0.f;
                #pragma unroll
                for (int c4 = 0; c4 < D / 4; ++c4) {
                    float4 v = *(const float4*)(row + 4 * c4);
                    sm = fmaf(v.x, v.x, sm); sm = fmaf(v.y, v.y, sm);
                    sm = fmaf(v.z, v.z, sm); sm = fmaf(v.w, v.w, sm);
                }
                xxj[tid] = sm;
            }
            __syncthreads();

            int tl = t0 - sbase;
            #pragma unroll 1
            for (int jj = 0; jj < TJ; jj += 2) {   // 2 j's: 8 acc chains
                const float* xr0 = xj + (size_t)jj * D;
                const float* xr1 = xr0 + D;
                int f0 = jj & 7, f1 = (jj + 1) & 7;
                float a0 = 0.f, a1 = 0.f, a2 = 0.f, a3 = 0.f;
                float b0 = 0.f, b1 = 0.f, b2 = 0.f, b3 = 0.f;
                #pragma unroll
                for (int c4 = 0; c4 < D / 4; ++c4) {   // broadcast b128
                    float4 v = *(const float4*)(xr0 + ((c4 ^ f0) * 4));
                    float4 w = *(const float4*)(xr1 + ((c4 ^ f1) * 4));
                    a0 = fmaf(xi[4 * c4 + 0], v.x, a0);
                    a1 = fmaf(xi[4 * c4 + 1], v.y, a1);
                    a2 = fmaf(xi[4 * c4 + 2], v.z, a2);
                    a3 = fmaf(xi[4 * c4 + 3], v.w, a3);
                    b0 = fmaf(xi[4 * c4 + 0], w.x, b0);
                    b1 = fmaf(xi[4 * c4 + 1], w.y, b1);
                    b2 = fmaf(xi[4 * c4 + 2], w.z, b2);
                    b3 = fmaf(xi[4 * c4 + 3], w.w, b3);
                }
                float dot0 = ((a0 + a1) + a2) + a3;
                float dot1 = ((b0 + b1) + b2) + b3;
                float da0 = __builtin_fmaf(-2.f, dot0, xxi + xxj[jj]);
                float da1 = __builtin_fmaf(-2.f, dot1, xxi + xxj[jj + 1]);
                chain(da0);
                chain(da1);
                float thr_a = a[20] + marg;
                bool w0 = da0 < thr_a, w1 = da1 < thr_a;
                if (__any((w0 || w1) && cnt >= M - 2)) compactAll();
                if (w0) {
                    if (cnt < M) {
                        ringd[cnt * 128 + tid] = da0;
                        ringj[cnt * 128 + tid] = (unsigned short)(tl + jj);
                        ++cnt;
                    } else ovf = true;
                }
                if (w1) {
                    if (cnt < M) {
                        ringd[cnt * 128 + tid] = da1;
                        ringj[cnt * 128 + tid] = (unsigned short)(tl + jj + 1);
                        ++cnt;
                    } else ovf = true;
                }
            }
        }
        compactAll();                       // final prune vs a[20]+marg
        if (ovf) {
            sc16[0] = 0xFFFFu;              // phase B: full exact rescan
        } else {
            sc16[0] = (unsigned short)cnt;
            #pragma unroll 1
            for (int k = 0; k < cnt; ++k) sc16[1 + k] = ringj[k * 128 + tid];
        }
    } else {
        // ================= D=5: r12 exact path verbatim =================
        float dl[21];
        int   il[21];
        #pragma unroll
        for (int t = 0; t < 21; ++t) { dl[t] = __builtin_inff(); il[t] = 0; }
        float thr = __builtin_inff();
        int   cnt = 0;
        auto drainR12 = [&]() {
            #pragma unroll 1
            for (int u = 0; __any(u < cnt); ++u) {
                if (u < cnt) {
                    float dd  = bufd[u * 128 + tid];
                    int   jj2 = (int)bufj[u * 128 + tid];
                    if (dd < dl[20]) {
                        dl[20] = dd; il[20] = jj2;
                        #pragma unroll
                        for (int t = 20; t > 0; --t) {
                            if (dl[t] < dl[t - 1]) {
                                float td = dl[t]; dl[t] = dl[t - 1]; dl[t - 1] = td;
                                int   ti = il[t]; il[t] = il[t - 1]; il[t - 1] = ti;
                            }
                        }
                    }
                }
            }
            cnt = 0;
            thr = dl[20];
        };

        #pragma unroll 1
        for (int t0 = sbase; t0 < sbase + JC; t0 += TJ) {
            __syncthreads();
            for (int e = tid; e < TJ * D; e += 128) {
                int r = e / D, c = e % D;
                xj[e] = fb[(size_t)(t0 + r) * RS + c];
            }
            if (tid < TJ) {
                const float* row = fb + (size_t)(t0 + tid) * RS;
                float sm = 0.f;
                #pragma unroll
                for (int c = 0; c < D; ++c) sm = fmaf(row[c], row[c], sm);
                xxj[tid] = sm;
            }
            __syncthreads();
            #pragma unroll 1
            for (int jj = 0; jj < TJ; ++jj) {
                float dot = 0.f;
                #pragma unroll
                for (int c = 0; c < D; ++c) dot = fmaf(xi[c], xj[jj * D + c], dot);
                float d = __builtin_fmaf(-2.f, dot, xxi + xxj[jj]);
                if (__any(cnt == B5)) drainR12();
                if (d < thr) {
                    bufd[cnt * 128 + tid] = d;
                    bufj[cnt * 128 + tid] = (unsigned short)(t0 + jj);
                    ++cnt;
                }
            }
        }
        drainR12();
        sc16[0] = 21;                       // exact top-21, rank order
        #pragma unroll
        for (int t = 0; t < 21; ++t)
            sc16[1 + t] = (unsigned short)(il[t] - sbase);
    }
}

// ===================== KNN phase B: exact merge ============================
// Candidates per split (j-ascending superset, or exact rank-ordered top-21
// for D=5); exact r12 fma chains; strict-< insertion == jax top_k
// stability. 0xFFFF split -> full exact rescan (sound fallback).
template <int D, int RS, int S>
__global__ __launch_bounds__(128) void knn_merge(
    const float* feat, const float* xcat, unsigned short* __restrict__ idxout) {
    constexpr int JC = NPTS / S;
    int gi = blockIdx.x * 128 + threadIdx.x;
    int b  = gi >> 13;
    int ib = gi & (NPTS - 1);
    const float* fb = feat + (size_t)b * NPTS * RS;

    float xi[D];
    if (D % 4 == 0) {
        #pragma unroll
        for (int c4 = 0; c4 < D / 4; ++c4) {
            float4 v = *(const float4*)(fb + (size_t)ib * RS + 4 * c4);
            xi[4 * c4] = v.x; xi[4 * c4 + 1] = v.y;
            xi[4 * c4 + 2] = v.z; xi[4 * c4 + 3] = v.w;
        }
    } else {
        #pragma unroll
        for (int c = 0; c < D; ++c) xi[c] = fb[(size_t)ib * RS + c];
    }
    float xxi = 0.f;
    #pragma unroll
    for (int c = 0; c < D; ++c) xxi = fmaf(xi[c], xi[c], xxi);

    const unsigned short* cp =
        (const unsigned short*)(xcat + (size_t)gi * 224 + 96);

    float dl[21];
    int   il[21];
    #pragma unroll
    for (int t = 0; t < 21; ++t) { dl[t] = __builtin_inff(); il[t] = 0; }

    auto ins = [&](int j) {                  // byte-identical r12 chain
        const float* row = fb + (size_t)j * RS;
        float dot = 0.f, xx = 0.f;
        if (D % 4 == 0) {
            #pragma unroll
            for (int c4 = 0; c4 < D / 4; ++c4) {
                float4 v = *(const float4*)(row + 4 * c4);
                dot = fmaf(xi[4 * c4], v.x, dot);     xx = fmaf(v.x, v.x, xx);
                dot = fmaf(xi[4 * c4 + 1], v.y, dot); xx = fmaf(v.y, v.y, xx);
                dot = fmaf(xi[4 * c4 + 2], v.z, dot); xx = fmaf(v.z, v.z, xx);
                dot = fmaf(xi[4 * c4 + 3], v.w, dot); xx = fmaf(v.w, v.w, xx);
            }
        } else {
            #pragma unroll
            for (int c = 0; c < D; ++c) {
                float v = row[c];
                dot = fmaf(xi[c], v, dot);
                xx  = fmaf(v, v, xx);
            }
        }
        float d = __builtin_fmaf(-2.f, dot, xxi + xx);
        if (d < dl[20]) {
            dl[20] = d; il[20] = j;
            #pragma unroll
            for (int u = 20; u > 0; --u) {
                if (dl[u] < dl[u - 1]) {
                    float td = dl[u]; dl[u] = dl[u - 1]; dl[u - 1] = td;
                    int   ti = il[u]; il[u] = il[u - 1]; il[u - 1] = ti;
                }
            }
        }
    };

    #pragma unroll 1
    for (int s = 0; s < S; ++s) {
        int cn = (int)cp[s * 32];
        if (cn == 0xFFFF) {                  // overflow: exact rescan
            #pragma unroll 1
            for (int j = s * JC; j < (s + 1) * JC; ++j) ins(j);
        } else {
            #pragma unroll 1
            for (int k = 0; k < cn; ++k)
                ins(s * JC + ((int)cp[s * 32 + 1 + k] & (JC - 1)));
        }
    }
    unsigned short* op = idxout + (size_t)gi * KNBR;
    #pragma unroll
    for (int t = 1; t < 21; ++t) op[t - 1] = (unsigned short)il[t];
}

// ===================== EdgeConv (fused BN + leaky + max_k) =================
template <int CIN, int RS, int COUT, int OTILE, int P>
__global__ __launch_bounds__(256) void edgeconv_kernel(
    const float* feat, const unsigned short* __restrict__ knn,
    const float* __restrict__ W, const float* __restrict__ g,
    const float* __restrict__ beta, const float* __restrict__ mu,
    const float* __restrict__ var,
    float* outb, int concat_off) {
    __shared__ float diff[P][KNBR][CIN];
    __shared__ float xil[P][CIN];
    __shared__ unsigned short kidx[P * KNBR];
    __shared__ float sl[OTILE], bl[OTILE], ml[OTILE];

    int tid = threadIdx.x;
    int h   = blockIdx.y;
    int n0  = blockIdx.x * P;                 // P divides 8192 -> same batch
    int b   = n0 >> 13;
    const float* fbase = feat + ((size_t)b << 13) * RS;

    for (int e = tid; e < P * CIN; e += 256)
        xil[e / CIN][e % CIN] = feat[(size_t)(n0 + e / CIN) * RS + e % CIN];
    for (int e = tid; e < P * KNBR; e += 256)
        kidx[e] = knn[(size_t)(n0 + e / KNBR) * KNBR + e % KNBR] & (NPTS - 1);
    for (int e = tid; e < OTILE; e += 256) {
        int o = h * OTILE + e;
        sl[e] = g[o] * rsqrtf(var[o] + 1e-5f);
        bl[e] = beta[o];
        ml[e] = mu[o];
    }
    __syncthreads();

    if (CIN % 4 == 0) {
        for (int e = tid; e < P * KNBR * (CIN / 4); e += 256) {
            int r = e / (CIN / 4), c4 = e % (CIN / 4);
            int p = r / KNBR, k = r % KNBR;
            int j = (int)kidx[r];
            float4 v = *(const float4*)(fbase + (size_t)j * RS + 4 * c4);
            diff[p][k][4 * c4 + 0] = v.x - xil[p][4 * c4 + 0];
            diff[p][k][4 * c4 + 1] = v.y - xil[p][4 * c4 + 1];
            diff[p][k][4 * c4 + 2] = v.z - xil[p][4 * c4 + 2];
            diff[p][k][4 * c4 + 3] = v.w - xil[p][4 * c4 + 3];
        }
    } else {
        for (int e = tid; e < P * KNBR * CIN; e += 256) {
            int r = e / CIN, c = e % CIN;
            int pp = r / KNBR, k = r % KNBR;
            int j = (int)kidx[r];
            diff[pp][k][c] = fbase[(size_t)j * RS + c] - xil[pp][c];
        }
    }
    __syncthreads();

    int ol = tid % OTILE, p = tid / OTILE;
    int o  = h * OTILE + ol;

    float wreg[CIN];
    #pragma unroll
    for (int c = 0; c < CIN; ++c) wreg[c] = W[(size_t)o * (2 * CIN) + c];
    float a = 0.f;
    #pragma unroll
    for (int c = 0; c < CIN; ++c) a = fmaf(wreg[c], xil[p][c], a);
    #pragma unroll
    for (int c = 0; c < CIN; ++c) wreg[c] = W[(size_t)o * (2 * CIN) + CIN + c];

    float s = sl[ol], mm = ml[ol], bb = bl[ol];
    float best = -__builtin_inff();
    for (int k = 0; k < KNBR; ++k) {
        float ac0 = a, ac1 = 0.f, ac2 = 0.f, ac3 = 0.f;
        #pragma unroll
        for (int c = 0; c < CIN; ++c) {
            float d = diff[p][k][c];
            if ((c & 3) == 0)      ac0 = fmaf(wreg[c], d, ac0);
            else if ((c & 3) == 1) ac1 = fmaf(wreg[c], d, ac1);
            else if ((c & 3) == 2) ac2 = fmaf(wreg[c], d, ac2);
            else                   ac3 = fmaf(wreg[c], d, ac3);
        }
        float acc = ((ac0 + ac1) + ac2) + ac3;
        float y = (acc - mm) * s + bb;
        y = (y >= 0.f) ? y : 0.2f * y;
        best = fmaxf(best, y);
    }
    outb[(size_t)(n0 + p) * 224 + concat_off + o] = best;
}

// ===================== conv_global: LDS-tiled GEMM + fused max =============
__global__ __launch_bounds__(256) void convglobal_kernel(
    const float* __restrict__ xcat,
    const float* __restrict__ Wg, const float* __restrict__ gg,
    const float* __restrict__ bg, const float* __restrict__ mg,
    const float* __restrict__ vg,
    float* __restrict__ partial) {
    const int KC = 56, PT = 64, OT = 64, ST = 68;   // ST: padded row stride
    __shared__ float flT[KC * ST];                  // [c][p]  15.2 KB
    __shared__ float WlT[KC * ST];                  // [c][o]  15.2 KB
    __shared__ float red[64 * 17];                  //          4.4 KB

    int tid = threadIdx.x;
    int oi  = tid & 15, pi = tid >> 4;
    int o0  = blockIdx.y * OT;
    int n0  = blockIdx.x * PT;                      // 64 | 8192 -> same batch
    int b   = n0 >> 13;
    int pchunk = blockIdx.x & 127;                  // chunk within batch

    float acc[4][4];
    #pragma unroll
    for (int u = 0; u < 4; ++u)
        #pragma unroll
        for (int v = 0; v < 4; ++v) acc[u][v] = 0.f;

    for (int kc = 0; kc < 224; kc += KC) {
        __syncthreads();
        for (int e = tid; e < PT * (KC / 4); e += 256) {
            int p = e / (KC / 4), c4 = e % (KC / 4);
            float4 v = *(const float4*)(xcat + (size_t)(n0 + p) * 224 + kc + 4 * c4);
            flT[(4 * c4 + 0) * ST + p] = v.x;
            flT[(4 * c4 + 1) * ST + p] = v.y;
            flT[(4 * c4 + 2) * ST + p] = v.z;
            flT[(4 * c4 + 3) * ST + p] = v.w;
        }
        for (int e = tid; e < OT * (KC / 4); e += 256) {
            int o = e / (KC / 4), c4 = e % (KC / 4);
            float4 v = *(const float4*)(Wg + (size_t)(o0 + o) * 224 + kc + 4 * c4);
            WlT[(4 * c4 + 0) * ST + o] = v.x;
            WlT[(4 * c4 + 1) * ST + o] = v.y;
            WlT[(4 * c4 + 2) * ST + o] = v.z;
            WlT[(4 * c4 + 3) * ST + o] = v.w;
        }
        __syncthreads();
        #pragma unroll 8
        for (int c = 0; c < KC; ++c) {
            float4 w4 = *(const float4*)(WlT + c * ST + oi * 4);
            float4 f4 = *(const float4*)(flT + c * ST + pi * 4);
            acc[0][0] = fmaf(w4.x, f4.x, acc[0][0]);
            acc[0][1] = fmaf(w4.x, f4.y, acc[0][1]);
            acc[0][2] = fmaf(w4.x, f4.z, acc[0][2]);
            acc[0][3] = fmaf(w4.x, f4.w, acc[0][3]);
            acc[1][0] = fmaf(w4.y, f4.x, acc[1][0]);
            acc[1][1] = fmaf(w4.y, f4.y, acc[1][1]);
            acc[1][2] = fmaf(w4.y, f4.z, acc[1][2]);
            acc[1][3] = fmaf(w4.y, f4.w, acc[1][3]);
            acc[2][0] = fmaf(w4.z, f4.x, acc[2][0]);
            acc[2][1] = fmaf(w4.z, f4.y, acc[2][1]);
            acc[2][2] = fmaf(w4.z, f4.z, acc[2][2]);
            acc[2][3] = fmaf(w4.z, f4.w, acc[2][3]);
            acc[3][0] = fmaf(w4.w, f4.x, acc[3][0]);
            acc[3][1] = fmaf(w4.w, f4.y, acc[3][1]);
            acc[3][2] = fmaf(w4.w, f4.z, acc[3][2]);
            acc[3][3] = fmaf(w4.w, f4.w, acc[3][3]);
        }
    }
    #pragma unroll
    for (int u = 0; u < 4; ++u) {
        int oL = oi * 4 + u, o = o0 + oL;
        float s = gg[o] * rsqrtf(vg[o] + 1e-5f);
        float mm = mg[o], bb = bg[o];
        float best = -__builtin_inff();
        #pragma unroll
        for (int v = 0; v < 4; ++v) {
            float y = (acc[u][v] - mm) * s + bb;
            y = (y >= 0.f) ? y : 0.2f * y;
            best = fmaxf(best, y);
        }
        red[oL * 17 + pi] = best;
    }
    __syncthreads();
    if (tid < 64) {
        float best = -__builtin_inff();
        #pragma unroll
        for (int q = 0; q < 16; ++q) best = fmaxf(best, red[tid * 17 + q]);
        partial[((size_t)(b * 128 + pchunk)) * 256 + o0 + tid] = best;
    }
}

__global__ void reduce_gfeat_kernel(const float* __restrict__ partial,
                                    float* __restrict__ gfeat,
                                    float* __restrict__ outg) {
    int b = blockIdx.x, o = threadIdx.x;
    float best = -__builtin_inff();
    for (int ch = 0; ch < 128; ++ch)
        best = fmaxf(best, partial[((size_t)b * 128 + ch) * 256 + o]);
    gfeat[b * 256 + o] = best;
    outg[b * 256 + o]  = best;
}

// ===================== heads (per-batch block) =============================
__global__ __launch_bounds__(256) void heads_kernel(
    const float* __restrict__ gfeat,
    const float* __restrict__ Wv1, const float* __restrict__ bv1,
    const float* __restrict__ Wv2, const float* __restrict__ bv2,
    const float* __restrict__ Wq1, const float* __restrict__ bq1,
    const float* __restrict__ Wq2, const float* __restrict__ bq2,
    float* __restrict__ out) {
    int b = blockIdx.x, t = threadIdx.x;
    __shared__ float gf[256], h[512], q[64];
    gf[t] = gfeat[b * 256 + t];
    __syncthreads();
    for (int r = t; r < 512; r += 256) {
        float acc = bv1[r];
        for (int c = 0; c < 256; ++c) acc = fmaf(Wv1[r * 256 + c], gf[c], acc);
        h[r] = fmaxf(acc, 0.f);
    }
    __syncthreads();
    if (t < 192) {
        float acc = bv2[t];
        for (int c = 0; c < 512; ++c) acc = fmaf(Wv2[t * 512 + c], h[c], acc);
        out[b * 192 + t] = acc;               // vertex_coords
    } else {
        int r = t - 192;
        if (r < 64) {
            float acc = bq1[r];
            for (int c = 0; c < 256; ++c) acc = fmaf(Wq1[r * 256 + c], gf[c], acc);
            q[r] = fmaxf(acc, 0.f);
        }
    }
    __syncthreads();
    if (t == 0) {
        float acc = bq2[0];
        for (int c = 0; c < 64; ++c) acc = fmaf(Wq2[c], q[c], acc);
        float nv = 1.0f / (1.0f + expf(-acc));
        out[772 + b] = nv;                                       // nvs
        float num = fminf(fmaxf(rintf(nv * 64.0f), 1.0f), 64.0f);
        out[768 + b] = num;                                      // num_vertices
    }
}

// ============================== launch =====================================
extern "C" void kernel_launch(void* const* d_in, const int* in_sizes, int n_in,
                              void* d_out, int out_size, void* d_ws, size_t ws_size,
                              hipStream_t stream) {
    (void)in_sizes; (void)n_in; (void)out_size; (void)ws_size;
    const float* x   = (const float*)d_in[0];
    const float* W1  = (const float*)d_in[1];
    const float* g1  = (const float*)d_in[2];
    const float* b1  = (const float*)d_in[3];
    const float* m1  = (const float*)d_in[4];
    const float* v1  = (const float*)d_in[5];
    const float* W2  = (const float*)d_in[6];
    const float* g2  = (const float*)d_in[7];
    const float* b2  = (const float*)d_in[8];
    const float* m2  = (const float*)d_in[9];
    const float* v2  = (const float*)d_in[10];
    const float* W3  = (const float*)d_in[11];
    const float* g3  = (const float*)d_in[12];
    const float* b3  = (const float*)d_in[13];
    const float* m3  = (const float*)d_in[14];
    const float* v3  = (const float*)d_in[15];
    const float* Wg  = (const float*)d_in[16];
    const float* gg  = (const float*)d_in[17];
    const float* bg  = (const float*)d_in[18];
    const float* mg  = (const float*)d_in[19];
    const float* vg  = (const float*)d_in[20];
    const float* Wv1 = (const float*)d_in[21];
    const float* bv1 = (const float*)d_in[22];
    const float* Wv2 = (const float*)d_in[23];
    const float* bv2 = (const float*)d_in[24];
    const float* Wq1 = (const float*)d_in[25];
    const float* bq1 = (const float*)d_in[26];
    const float* Wq2 = (const float*)d_in[27];
    const float* bq2 = (const float*)d_in[28];

    float* out  = (float*)d_out;
    float* xcat = out + 1800;                    // f32 [4,8192,224]
    char* ws = (char*)d_ws;
    const int ROWS = BATCH * NPTS;   // 32768

    // ws layout (1,310,720 B; part/gft alias idx AFTER it is dead):
    unsigned short* idx  = (unsigned short*)(ws);        // [32768,20] u16
    float*          part = (float*)(ws);                 // [512,256] f32 (alias)
    float*          gft  = (float*)(ws + 524288);        // [4,256]   f32 (alias)

    // ---- EdgeConv 1: 5 -> 32
    knn_part<5, 5, 8, 128, 28><<<dim3(ROWS / 128, 8), 128, 0, stream>>>(x, xcat);
    knn_merge<5, 5, 8><<<ROWS / 128, 128, 0, stream>>>(x, xcat, idx);
    edgeconv_kernel<5, 5, 32, 32, 8>
        <<<dim3(ROWS / 8, 1), 256, 0, stream>>>(x, idx, W1, g1, b1, m1, v1, xcat, 0);

    // ---- EdgeConv 2: 32 -> 64 (features from xcat[:,0:32))
    knn_part<32, 224, 8, 128, 28><<<dim3(ROWS / 128, 8), 128, 0, stream>>>(xcat, xcat);
    knn_merge<32, 224, 8><<<ROWS / 128, 128, 0, stream>>>(xcat, xcat, idx);
    edgeconv_kernel<32, 224, 64, 64, 4>
        <<<dim3(ROWS / 4, 1), 256, 0, stream>>>(xcat, idx, W2, g2, b2, m2, v2, xcat, 32);

    // ---- EdgeConv 3: 64 -> 128 (features from xcat[:,32:96))
    knn_part<64, 224, 8, 64, 28><<<dim3(ROWS / 128, 8), 128, 0, stream>>>(xcat + 32, xcat);
    knn_merge<64, 224, 8><<<ROWS / 128, 128, 0, stream>>>(xcat + 32, xcat, idx);
    edgeconv_kernel<64, 224, 128, 64, 4>
        <<<dim3(ROWS / 4, 2), 256, 0, stream>>>(xcat + 32, idx, W3, g3, b3, m3, v3, xcat, 96);

    // ---- conv_global (224->256) + max over N  (idx dead; part aliases it)
    convglobal_kernel<<<dim3(ROWS / 64, 4), 256, 0, stream>>>(
        xcat, Wg, gg, bg, mg, vg, part);
    reduce_gfeat_kernel<<<BATCH, 256, 0, stream>>>(part, gft, out + 776);

    // ---- heads
    heads_kernel<<<BATCH, 256, 0, stream>>>(
        gft, Wv1, bv1, Wv2, bv2, Wq1, bq1, Wq2, bq2, out);
}

// Round 9
// 4218.874 us; speedup vs baseline: 1.3573x; 1.3573x over previous
//
#include <hip/hip_runtime.h>
#include <hip/hip_bf16.h>

// ---------------------------------------------------------------------------
// BasicDGCNN forward, MI355X (gfx950). Inputs f32, output f32.
// Output layout (f32, flat): [0,768) vertex | [768,772) num_vertices |
// [772,776) nvs | [776,1800) gfeat | [1800,..) x_concat [4,8192,224].
//
// Round-20: the filter program (r13-r19) is dead -- every phase-A design
// with per-j bookkeeping lost to plain r12 (best 3783us). r12's counters:
// VALUBusy 52%, latency-bound on the SERIAL per-j fma chain (dep ~4cyc x D)
// with ILP~1. Single surgical change: scan JU j's per iteration with JU
// INDEPENDENT byte-identical serial chains (JU=4 @D=32, 2 @D=64). Buffer/
// drain/threshold logic untouched (drain-timing shifts provably don't
// change the top-21: thr is a stale >= copy of dl[20], superset filter,
// FIFO j-ascending insertion). B 8->12 (LDS 26.1KB, still 6 blk/CU),
// __launch_bounds__(128,2) vs D=64 spills. D=5 path + knn_merge +
// edgeconv + convglobal + heads are r12 VERBATIM. absmax must stay
// 0.2949219 exactly (any drift = chain-order bug = failure).
// ---------------------------------------------------------------------------

#define NPTS 8192
#define BATCH 4
#define KNBR 20

// ===================== KNN phase A: per-split top-21 =======================
// grid (ROWS/128, S); block 128 thr; thread = query point; j-range
// [s*1024,(s+1)*1024) staged in TJ-row LDS tiles. dist = xxi+xxj-2dot,
// ascending-c fma chains (bitwise-matched by knn_merge). Deferred buffered
// selection: stale per-thread threshold + B-slot LDS buffer, drained through
// the exact insertion chain when near-full (__any) — bit-exact vs direct
// insertion (superset filter; drain re-checks in j-ascending order).
// JU independent chains per iteration attack the dep-latency (4cyc/fma).
template <int D, int RS, int S, int TJ, int B, int JU>
__global__ __launch_bounds__(128, 2) void knn_part(
    const float* feat, float* xcat) {
    __shared__ float xj[TJ * D];
    __shared__ float xxj[TJ];
    __shared__ float bufd[B * 128];            // [slot][lane]: stride-1
    __shared__ unsigned short bufj[B * 128];   // u16: 2 lanes/bank = free
    const int JC = NPTS / S;

    int gi = blockIdx.x * 128 + threadIdx.x;
    int s  = blockIdx.y;
    int b  = gi >> 13;
    int ib = gi & (NPTS - 1);
    const float* fb = feat + (size_t)b * NPTS * RS;
    int tid = threadIdx.x;

    float xi[D];
    if (D % 4 == 0) {
        #pragma unroll
        for (int c4 = 0; c4 < D / 4; ++c4) {
            float4 v = *(const float4*)(fb + (size_t)ib * RS + 4 * c4);
            xi[4 * c4] = v.x; xi[4 * c4 + 1] = v.y;
            xi[4 * c4 + 2] = v.z; xi[4 * c4 + 3] = v.w;
        }
    } else {
        #pragma unroll
        for (int c = 0; c < D; ++c) xi[c] = fb[(size_t)ib * RS + c];
    }
    float xxi = 0.f;
    #pragma unroll
    for (int c = 0; c < D; ++c) xxi = fmaf(xi[c], xi[c], xxi);

    float dl[21];
    int   il[21];
    #pragma unroll
    for (int t = 0; t < 21; ++t) { dl[t] = __builtin_inff(); il[t] = 0; }

    float thr = __builtin_inff();          // stale copy of dl[20]
    int   cnt = 0;

    auto drain = [&]() {
        #pragma unroll 1
        for (int u = 0; __any(u < cnt); ++u) {
            if (u < cnt) {
                float dd  = bufd[u * 128 + tid];
                int   jj2 = (int)bufj[u * 128 + tid];
                if (dd < dl[20]) {         // strict: ties keep earlier j
                    dl[20] = dd; il[20] = jj2;
                    #pragma unroll
                    for (int t = 20; t > 0; --t) {
                        if (dl[t] < dl[t - 1]) {
                            float td = dl[t]; dl[t] = dl[t - 1]; dl[t - 1] = td;
                            int   ti = il[t]; il[t] = il[t - 1]; il[t - 1] = ti;
                        }
                    }
                }
            }
        }
        cnt = 0;
        thr = dl[20];
    };

    #pragma unroll 1
    for (int j0 = s * JC; j0 < (s + 1) * JC; j0 += TJ) {
        __syncthreads();                   // protect prior-iter reads
        if (D % 4 == 0) {
            for (int e = tid; e < TJ * (D / 4); e += 128) {
                int r = e / (D / 4), c4 = e % (D / 4);
                float4 v = *(const float4*)(fb + (size_t)(j0 + r) * RS + 4 * c4);
                *(float4*)(xj + r * D + 4 * c4) = v;
            }
        } else {
            for (int e = tid; e < TJ * D; e += 128) {
                int r = e / D, c = e % D;
                xj[e] = fb[(size_t)(j0 + r) * RS + c];
            }
        }
        // norms from GLOBAL (ascending-c fma chain == knn_merge's recompute)
        if (tid < TJ) {
            const float* row = fb + (size_t)(j0 + tid) * RS;
            float sm = 0.f;
            if (D % 4 == 0) {
                #pragma unroll
                for (int c4 = 0; c4 < D / 4; ++c4) {
                    float4 v = *(const float4*)(row + 4 * c4);
                    sm = fmaf(v.x, v.x, sm); sm = fmaf(v.y, v.y, sm);
                    sm = fmaf(v.z, v.z, sm); sm = fmaf(v.w, v.w, sm);
                }
            } else {
                #pragma unroll
                for (int c = 0; c < D; ++c) sm = fmaf(row[c], row[c], sm);
            }
            xxj[tid] = sm;
        }
        __syncthreads();

        if (D % 4 == 0) {
            // ---- JU independent byte-identical serial chains ----
            #pragma unroll 1
            for (int jj = 0; jj < TJ; jj += JU) {
                if (__any(cnt > B - JU)) drain();
                float dots[JU];
                #pragma unroll
                for (int u = 0; u < JU; ++u) dots[u] = 0.f;
                #pragma unroll
                for (int c4 = 0; c4 < D / 4; ++c4) {   // broadcast b128
                    #pragma unroll
                    for (int u = 0; u < JU; ++u) {
                        float4 v = *(const float4*)(xj + (jj + u) * D + 4 * c4);
                        dots[u] = fmaf(xi[4 * c4 + 0], v.x, dots[u]);
                        dots[u] = fmaf(xi[4 * c4 + 1], v.y, dots[u]);
                        dots[u] = fmaf(xi[4 * c4 + 2], v.z, dots[u]);
                        dots[u] = fmaf(xi[4 * c4 + 3], v.w, dots[u]);
                    }
                }
                #pragma unroll
                for (int u = 0; u < JU; ++u) {
                    float d = __builtin_fmaf(-2.f, dots[u], xxi + xxj[jj + u]);
                    if (d < thr) {         // stale thr >= dl[20]: superset
                        bufd[cnt * 128 + tid] = d;
                        bufj[cnt * 128 + tid] = (unsigned short)(j0 + jj + u);
                        ++cnt;
                    }
                }
            }
        } else {
            // ---- D=5: r12 per-j path verbatim ----
            #pragma unroll 1
            for (int jj = 0; jj < TJ; ++jj) {
                float dot = 0.f;
                #pragma unroll
                for (int c = 0; c < D; ++c) dot = fmaf(xi[c], xj[jj * D + c], dot);
                float d = __builtin_fmaf(-2.f, dot, xxi + xxj[jj]);
                if (__any(cnt == B)) drain();
                if (d < thr) {
                    bufd[cnt * 128 + tid] = d;
                    bufj[cnt * 128 + tid] = (unsigned short)(j0 + jj);
                    ++cnt;
                }
            }
        }
    }
    // final drain
    drain();

    unsigned short* cp =
        (unsigned short*)(xcat + (size_t)gi * 224 + 96) + s * 21;
    #pragma unroll
    for (int t = 0; t < 21; ++t) cp[t] = (unsigned short)il[t];
}

// ===================== KNN phase B: merge S x 21 candidates ================
// Recompute d with the SAME fma ordering as knn_part; insert candidates in
// (split asc, stored rank) order with strict < -> stability == jax top_k.
// Drop entry 0 (self).
template <int D, int RS, int S>
__global__ __launch_bounds__(256) void knn_merge(
    const float* feat, const float* xcat, unsigned short* __restrict__ idxout) {
    int gi = blockIdx.x * 256 + threadIdx.x;
    int b  = gi >> 13;
    int ib = gi & (NPTS - 1);
    const float* fb = feat + (size_t)b * NPTS * RS;

    float xi[D];
    if (D % 4 == 0) {
        #pragma unroll
        for (int c4 = 0; c4 < D / 4; ++c4) {
            float4 v = *(const float4*)(fb + (size_t)ib * RS + 4 * c4);
            xi[4 * c4] = v.x; xi[4 * c4 + 1] = v.y;
            xi[4 * c4 + 2] = v.z; xi[4 * c4 + 3] = v.w;
        }
    } else {
        #pragma unroll
        for (int c = 0; c < D; ++c) xi[c] = fb[(size_t)ib * RS + c];
    }
    float xxi = 0.f;
    #pragma unroll
    for (int c = 0; c < D; ++c) xxi = fmaf(xi[c], xi[c], xxi);

    const unsigned short* cp =
        (const unsigned short*)(xcat + (size_t)gi * 224 + 96);

    float dl[21];
    int   il[21];
    #pragma unroll
    for (int t = 0; t < 21; ++t) { dl[t] = __builtin_inff(); il[t] = 0; }

    for (int t = 0; t < S * 21; ++t) {
        int j = ((int)cp[t]) & (NPTS - 1);
        const float* row = fb + (size_t)j * RS;
        float dot = 0.f, xx = 0.f;
        if (D % 4 == 0) {
            #pragma unroll
            for (int c4 = 0; c4 < D / 4; ++c4) {
                float4 v = *(const float4*)(row + 4 * c4);
                dot = fmaf(xi[4 * c4], v.x, dot);     xx = fmaf(v.x, v.x, xx);
                dot = fmaf(xi[4 * c4 + 1], v.y, dot); xx = fmaf(v.y, v.y, xx);
                dot = fmaf(xi[4 * c4 + 2], v.z, dot); xx = fmaf(v.z, v.z, xx);
                dot = fmaf(xi[4 * c4 + 3], v.w, dot); xx = fmaf(v.w, v.w, xx);
            }
        } else {
            #pragma unroll
            for (int c = 0; c < D; ++c) {
                float v = row[c];
                dot = fmaf(xi[c], v, dot);
                xx  = fmaf(v, v, xx);
            }
        }
        float d = __builtin_fmaf(-2.f, dot, xxi + xx);
        if (d < dl[20]) {
            dl[20] = d; il[20] = j;
            #pragma unroll
            for (int u = 20; u > 0; --u) {
                if (dl[u] < dl[u - 1]) {
                    float td = dl[u]; dl[u] = dl[u - 1]; dl[u - 1] = td;
                    int   ti = il[u]; il[u] = il[u - 1]; il[u - 1] = ti;
                }
            }
        }
    }
    unsigned short* op = idxout + (size_t)gi * KNBR;
    #pragma unroll
    for (int t = 1; t < 21; ++t) op[t - 1] = (unsigned short)il[t];
}

// ===================== EdgeConv (fused BN + leaky + max_k) =================
template <int CIN, int RS, int COUT, int OTILE, int P>
__global__ __launch_bounds__(256) void edgeconv_kernel(
    const float* feat, const unsigned short* __restrict__ knn,
    const float* __restrict__ W, const float* __restrict__ g,
    const float* __restrict__ beta, const float* __restrict__ mu,
    const float* __restrict__ var,
    float* outb, int concat_off) {
    __shared__ float diff[P][KNBR][CIN];
    __shared__ float xil[P][CIN];
    __shared__ unsigned short kidx[P * KNBR];
    __shared__ float sl[OTILE], bl[OTILE], ml[OTILE];

    int tid = threadIdx.x;
    int h   = blockIdx.y;
    int n0  = blockIdx.x * P;                 // P divides 8192 -> same batch
    int b   = n0 >> 13;
    const float* fbase = feat + ((size_t)b << 13) * RS;

    for (int e = tid; e < P * CIN; e += 256)
        xil[e / CIN][e % CIN] = feat[(size_t)(n0 + e / CIN) * RS + e % CIN];
    for (int e = tid; e < P * KNBR; e += 256)
        kidx[e] = knn[(size_t)(n0 + e / KNBR) * KNBR + e % KNBR] & (NPTS - 1);
    for (int e = tid; e < OTILE; e += 256) {
        int o = h * OTILE + e;
        sl[e] = g[o] * rsqrtf(var[o] + 1e-5f);
        bl[e] = beta[o];
        ml[e] = mu[o];
    }
    __syncthreads();

    if (CIN % 4 == 0) {
        for (int e = tid; e < P * KNBR * (CIN / 4); e += 256) {
            int r = e / (CIN / 4), c4 = e % (CIN / 4);
            int p = r / KNBR, k = r % KNBR;
            int j = (int)kidx[r];
            float4 v = *(const float4*)(fbase + (size_t)j * RS + 4 * c4);
            diff[p][k][4 * c4 + 0] = v.x - xil[p][4 * c4 + 0];
            diff[p][k][4 * c4 + 1] = v.y - xil[p][4 * c4 + 1];
            diff[p][k][4 * c4 + 2] = v.z - xil[p][4 * c4 + 2];
            diff[p][k][4 * c4 + 3] = v.w - xil[p][4 * c4 + 3];
        }
    } else {
        for (int e = tid; e < P * KNBR * CIN; e += 256) {
            int r = e / CIN, c = e % CIN;
            int pp = r / KNBR, k = r % KNBR;
            int j = (int)kidx[r];
            diff[pp][k][c] = fbase[(size_t)j * RS + c] - xil[pp][c];
        }
    }
    __syncthreads();

    int ol = tid % OTILE, p = tid / OTILE;
    int o  = h * OTILE + ol;

    float wreg[CIN];
    #pragma unroll
    for (int c = 0; c < CIN; ++c) wreg[c] = W[(size_t)o * (2 * CIN) + c];
    float a = 0.f;
    #pragma unroll
    for (int c = 0; c < CIN; ++c) a = fmaf(wreg[c], xil[p][c], a);
    #pragma unroll
    for (int c = 0; c < CIN; ++c) wreg[c] = W[(size_t)o * (2 * CIN) + CIN + c];

    float s = sl[ol], mm = ml[ol], bb = bl[ol];
    float best = -__builtin_inff();
    for (int k = 0; k < KNBR; ++k) {
        float ac0 = a, ac1 = 0.f, ac2 = 0.f, ac3 = 0.f;
        #pragma unroll
        for (int c = 0; c < CIN; ++c) {
            float d = diff[p][k][c];
            if ((c & 3) == 0)      ac0 = fmaf(wreg[c], d, ac0);
            else if ((c & 3) == 1) ac1 = fmaf(wreg[c], d, ac1);
            else if ((c & 3) == 2) ac2 = fmaf(wreg[c], d, ac2);
            else                   ac3 = fmaf(wreg[c], d, ac3);
        }
        float acc = ((ac0 + ac1) + ac2) + ac3;
        float y = (acc - mm) * s + bb;
        y = (y >= 0.f) ? y : 0.2f * y;
        best = fmaxf(best, y);
    }
    outb[(size_t)(n0 + p) * 224 + concat_off + o] = best;
}

// ===================== conv_global: LDS-tiled GEMM + fused max =============
__global__ __launch_bounds__(256) void convglobal_kernel(
    const float* __restrict__ xcat,
    const float* __restrict__ Wg, const float* __restrict__ gg,
    const float* __restrict__ bg, const float* __restrict__ mg,
    const float* __restrict__ vg,
    float* __restrict__ partial) {
    const int KC = 56, PT = 64, OT = 64, ST = 68;   // ST: padded row stride
    __shared__ float flT[KC * ST];                  // [c][p]  15.2 KB
    __shared__ float WlT[KC * ST];                  // [c][o]  15.2 KB
    __shared__ float red[64 * 17];                  //          4.4 KB

    int tid = threadIdx.x;
    int oi  = tid & 15, pi = tid >> 4;
    int o0  = blockIdx.y * OT;
    int n0  = blockIdx.x * PT;                      // 64 | 8192 -> same batch
    int b   = n0 >> 13;
    int pchunk = blockIdx.x & 127;                  // chunk within batch

    float acc[4][4];
    #pragma unroll
    for (int u = 0; u < 4; ++u)
        #pragma unroll
        for (int v = 0; v < 4; ++v) acc[u][v] = 0.f;

    for (int kc = 0; kc < 224; kc += KC) {
        __syncthreads();
        for (int e = tid; e < PT * (KC / 4); e += 256) {
            int p = e / (KC / 4), c4 = e % (KC / 4);
            float4 v = *(const float4*)(xcat + (size_t)(n0 + p) * 224 + kc + 4 * c4);
            flT[(4 * c4 + 0) * ST + p] = v.x;
            flT[(4 * c4 + 1) * ST + p] = v.y;
            flT[(4 * c4 + 2) * ST + p] = v.z;
            flT[(4 * c4 + 3) * ST + p] = v.w;
        }
        for (int e = tid; e < OT * (KC / 4); e += 256) {
            int o = e / (KC / 4), c4 = e % (KC / 4);
            float4 v = *(const float4*)(Wg + (size_t)(o0 + o) * 224 + kc + 4 * c4);
            WlT[(4 * c4 + 0) * ST + o] = v.x;
            WlT[(4 * c4 + 1) * ST + o] = v.y;
            WlT[(4 * c4 + 2) * ST + o] = v.z;
            WlT[(4 * c4 + 3) * ST + o] = v.w;
        }
        __syncthreads();
        #pragma unroll 8
        for (int c = 0; c < KC; ++c) {
            float4 w4 = *(const float4*)(WlT + c * ST + oi * 4);
            float4 f4 = *(const float4*)(flT + c * ST + pi * 4);
            acc[0][0] = fmaf(w4.x, f4.x, acc[0][0]);
            acc[0][1] = fmaf(w4.x, f4.y, acc[0][1]);
            acc[0][2] = fmaf(w4.x, f4.z, acc[0][2]);
            acc[0][3] = fmaf(w4.x, f4.w, acc[0][3]);
            acc[1][0] = fmaf(w4.y, f4.x, acc[1][0]);
            acc[1][1] = fmaf(w4.y, f4.y, acc[1][1]);
            acc[1][2] = fmaf(w4.y, f4.z, acc[1][2]);
            acc[1][3] = fmaf(w4.y, f4.w, acc[1][3]);
            acc[2][0] = fmaf(w4.z, f4.x, acc[2][0]);
            acc[2][1] = fmaf(w4.z, f4.y, acc[2][1]);
            acc[2][2] = fmaf(w4.z, f4.z, acc[2][2]);
            acc[2][3] = fmaf(w4.z, f4.w, acc[2][3]);
            acc[3][0] = fmaf(w4.w, f4.x, acc[3][0]);
            acc[3][1] = fmaf(w4.w, f4.y, acc[3][1]);
            acc[3][2] = fmaf(w4.w, f4.z, acc[3][2]);
            acc[3][3] = fmaf(w4.w, f4.w, acc[3][3]);
        }
    }
    #pragma unroll
    for (int u = 0; u < 4; ++u) {
        int oL = oi * 4 + u, o = o0 + oL;
        float s = gg[o] * rsqrtf(vg[o] + 1e-5f);
        float mm = mg[o], bb = bg[o];
        float best = -__builtin_inff();
        #pragma unroll
        for (int v = 0; v < 4; ++v) {
            float y = (acc[u][v] - mm) * s + bb;
            y = (y >= 0.f) ? y : 0.2f * y;
            best = fmaxf(best, y);
        }
        red[oL * 17 + pi] = best;
    }
    __syncthreads();
    if (tid < 64) {
        float best = -__builtin_inff();
        #pragma unroll
        for (int q = 0; q < 16; ++q) best = fmaxf(best, red[tid * 17 + q]);
        partial[((size_t)(b * 128 + pchunk)) * 256 + o0 + tid] = best;
    }
}

__global__ void reduce_gfeat_kernel(const float* __restrict__ partial,
                                    float* __restrict__ gfeat,
                                    float* __restrict__ outg) {
    int b = blockIdx.x, o = threadIdx.x;
    float best = -__builtin_inff();
    for (int ch = 0; ch < 128; ++ch)
        best = fmaxf(best, partial[((size_t)b * 128 + ch) * 256 + o]);
    gfeat[b * 256 + o] = best;
    outg[b * 256 + o]  = best;
}

// ===================== heads (per-batch block) =============================
__global__ __launch_bounds__(256) void heads_kernel(
    const float* __restrict__ gfeat,
    const float* __restrict__ Wv1, const float* __restrict__ bv1,
    const float* __restrict__ Wv2, const float* __restrict__ bv2,
    const float* __restrict__ Wq1, const float* __restrict__ bq1,
    const float* __restrict__ Wq2, const float* __restrict__ bq2,
    float* __restrict__ out) {
    int b = blockIdx.x, t = threadIdx.x;
    __shared__ float gf[256], h[512], q[64];
    gf[t] = gfeat[b * 256 + t];
    __syncthreads();
    for (int r = t; r < 512; r += 256) {
        float acc = bv1[r];
        for (int c = 0; c < 256; ++c) acc = fmaf(Wv1[r * 256 + c], gf[c], acc);
        h[r] = fmaxf(acc, 0.f);
    }
    __syncthreads();
    if (t < 192) {
        float acc = bv2[t];
        for (int c = 0; c < 512; ++c) acc = fmaf(Wv2[t * 512 + c], h[c], acc);
        out[b * 192 + t] = acc;               // vertex_coords
    } else {
        int r = t - 192;
        if (r < 64) {
            float acc = bq1[r];
            for (int c = 0; c < 256; ++c) acc = fmaf(Wq1[r * 256 + c], gf[c], acc);
            q[r] = fmaxf(acc, 0.f);
        }
    }
    __syncthreads();
    if (t == 0) {
        float acc = bq2[0];
        for (int c = 0; c < 64; ++c) acc = fmaf(Wq2[c], q[c], acc);
        float nv = 1.0f / (1.0f + expf(-acc));
        out[772 + b] = nv;                                       // nvs
        float num = fminf(fmaxf(rintf(nv * 64.0f), 1.0f), 64.0f);
        out[768 + b] = num;                                      // num_vertices
    }
}

// ============================== launch =====================================
extern "C" void kernel_launch(void* const* d_in, const int* in_sizes, int n_in,
                              void* d_out, int out_size, void* d_ws, size_t ws_size,
                              hipStream_t stream) {
    (void)in_sizes; (void)n_in; (void)out_size; (void)ws_size;
    const float* x   = (const float*)d_in[0];
    const float* W1  = (const float*)d_in[1];
    const float* g1  = (const float*)d_in[2];
    const float* b1  = (const float*)d_in[3];
    const float* m1  = (const float*)d_in[4];
    const float* v1  = (const float*)d_in[5];
    const float* W2  = (const float*)d_in[6];
    const float* g2  = (const float*)d_in[7];
    const float* b2  = (const float*)d_in[8];
    const float* m2  = (const float*)d_in[9];
    const float* v2  = (const float*)d_in[10];
    const float* W3  = (const float*)d_in[11];
    const float* g3  = (const float*)d_in[12];
    const float* b3  = (const float*)d_in[13];
    const float* m3  = (const float*)d_in[14];
    const float* v3  = (const float*)d_in[15];
    const float* Wg  = (const float*)d_in[16];
    const float* gg  = (const float*)d_in[17];
    const float* bg  = (const float*)d_in[18];
    const float* mg  = (const float*)d_in[19];
    const float* vg  = (const float*)d_in[20];
    const float* Wv1 = (const float*)d_in[21];
    const float* bv1 = (const float*)d_in[22];
    const float* Wv2 = (const float*)d_in[23];
    const float* bv2 = (const float*)d_in[24];
    const float* Wq1 = (const float*)d_in[25];
    const float* bq1 = (const float*)d_in[26];
    const float* Wq2 = (const float*)d_in[27];
    const float* bq2 = (const float*)d_in[28];

    float* out  = (float*)d_out;
    float* xcat = out + 1800;                    // f32 [4,8192,224]
    char* ws = (char*)d_ws;
    const int ROWS = BATCH * NPTS;   // 32768

    // ws layout (1,310,720 B; part/gft alias idx AFTER it is dead):
    unsigned short* idx  = (unsigned short*)(ws);        // [32768,20] u16
    float*          part = (float*)(ws);                 // [512,256] f32 (alias)
    float*          gft  = (float*)(ws + 524288);        // [4,256]   f32 (alias)

    // ---- EdgeConv 1: 5 -> 32
    knn_part<5, 5, 8, 128, 8, 1><<<dim3(ROWS / 128, 8), 128, 0, stream>>>(x, xcat);
    knn_merge<5, 5, 8><<<ROWS / 256, 256, 0, stream>>>(x, xcat, idx);
    edgeconv_kernel<5, 5, 32, 32, 8>
        <<<dim3(ROWS / 8, 1), 256, 0, stream>>>(x, idx, W1, g1, b1, m1, v1, xcat, 0);

    // ---- EdgeConv 2: 32 -> 64 (features from xcat[:,0:32))
    knn_part<32, 224, 8, 128, 12, 4><<<dim3(ROWS / 128, 8), 128, 0, stream>>>(xcat, xcat);
    knn_merge<32, 224, 8><<<ROWS / 256, 256, 0, stream>>>(xcat, xcat, idx);
    edgeconv_kernel<32, 224, 64, 64, 4>
        <<<dim3(ROWS / 4, 1), 256, 0, stream>>>(xcat, idx, W2, g2, b2, m2, v2, xcat, 32);

    // ---- EdgeConv 3: 64 -> 128 (features from xcat[:,32:96))
    knn_part<64, 224, 8, 64, 12, 2><<<dim3(ROWS / 128, 8), 128, 0, stream>>>(xcat + 32, xcat);
    knn_merge<64, 224, 8><<<ROWS / 256, 256, 0, stream>>>(xcat + 32, xcat, idx);
    edgeconv_kernel<64, 224, 128, 64, 4>
        <<<dim3(ROWS / 4, 2), 256, 0, stream>>>(xcat + 32, idx, W3, g3, b3, m3, v3, xcat, 96);

    // ---- conv_global (224->256) + max over N  (idx dead; part aliases it)
    convglobal_kernel<<<dim3(ROWS / 64, 4), 256, 0, stream>>>(
        xcat, Wg, gg, bg, mg, vg, part);
    reduce_gfeat_kernel<<<BATCH, 256, 0, stream>>>(part, gft, out + 776);

    // ---- heads
    heads_kernel<<<BATCH, 256, 0, stream>>>(
        gft, Wv1, bv1, Wv2, bv2, Wq1, bq1, Wq2, bq2, out);
}